// Round 10
// baseline (232.207 us; speedup 1.0000x reference)
//
#include <hip/hip_runtime.h>

#define NF 128
#define OUTF 64

// mark bits
#define M2 1   // layer-2 frontier (in-neighbors of last, + last)
#define M1 2   // layer-1 frontier

// capacity caps (expected ~13 / ~190 / ~2600; huge slack)
#define CAP_F2 2048
#define CAP_E3 4096
#define CAP_F1 32768
#define CAP_E2 65536

// cnt[0]=F2, cnt[1]=E3, cnt[2]=F1, cnt[3]=E2

__device__ __forceinline__ void zero_row(float* A, int v) {
    float4* r = (float4*)(A + (size_t)v * NF);
    #pragma unroll
    for (int k = 0; k < 32; ++k) r[k] = make_float4(0.f, 0.f, 0.f, 0.f);
}

// wave-cooperative GEMV + scatter: AGG[d] += w * (xrow(s) @ W[LDS])
__device__ __forceinline__ void gemv_scatter(
    const float* __restrict__ Xin, int s, float w, int d,
    float (&wsm)[128][128], int lane, float* __restrict__ AGG)
{
    size_t so = (size_t)s * NF;
    float x0 = Xin[so + lane];
    float x1 = Xin[so + lane + 64];
    float a0 = 0.f, a1 = 0.f;
    #pragma unroll 16
    for (int k = 0; k < 64; ++k) {
        float xk = __shfl(x0, k);
        a0 += xk * wsm[k][lane];
        a1 += xk * wsm[k][lane + 64];
    }
    #pragma unroll 16
    for (int k = 0; k < 64; ++k) {
        float xk = __shfl(x1, k);
        a0 += xk * wsm[k + 64][lane];
        a1 += xk * wsm[k + 64][lane + 64];
    }
    size_t off = (size_t)d * NF;
    atomicAdd(&AGG[off + lane],      w * a0);
    atomicAdd(&AGG[off + lane + 64], w * a1);
}

// ---------------------------------------------------------------------------
// scan1: unconditional in-degree + level-1 (dst == last) + seed; zeroes
// AGG2 rows at F2-insert time.
// ---------------------------------------------------------------------------
__global__ void k_scan1(const int* __restrict__ src, const int* __restrict__ dst,
                        int E, int last, int* __restrict__ mark, int* __restrict__ deg,
                        int* __restrict__ cnt, int* __restrict__ F2,
                        int2* __restrict__ E3l, int2* __restrict__ E2l,
                        float* __restrict__ AGG2)
{
    const int gtid = blockIdx.x * blockDim.x + threadIdx.x;
    if (gtid == 0) {
        atomicOr(&mark[last], M2);
        int q = atomicAdd(&cnt[0], 1);
        if (q < CAP_F2) F2[q] = last;
        zero_row(AGG2, last);
        int r = atomicAdd(&cnt[3], 1);                 // self-loop edge in E2
        if (r < CAP_E2) E2l[r] = make_int2(last, last);
        int e = atomicAdd(&cnt[1], 1);                 // self-loop edge in E3
        if (e < CAP_E3) E3l[e] = make_int2(last, last);
    }

    auto hit = [&](int d, int i) {
        atomicAdd(&deg[d], 1);                         // in-degree, all nodes
        if (d == last) {
            int s = src[i];
            int p = atomicAdd(&cnt[1], 1);
            if (p < CAP_E3) E3l[p] = make_int2(s, d);
            if (s != last && !(atomicOr(&mark[s], M2) & M2)) {
                int q = atomicAdd(&cnt[0], 1);
                if (q < CAP_F2) F2[q] = s;
                zero_row(AGG2, s);
                int r = atomicAdd(&cnt[3], 1);         // self-loop edge in E2
                if (r < CAP_E2) E2l[r] = make_int2(s, s);
            }
        }
    };

    const int nq = E >> 2;
    if ((((uintptr_t)dst) & 15) == 0) {
        if (gtid < nq) {
            int4 d4 = ((const int4*)dst)[gtid];
            int i = gtid << 2;
            hit(d4.x, i); hit(d4.y, i + 1); hit(d4.z, i + 2); hit(d4.w, i + 3);
        }
        if (gtid == 0)
            for (int i = nq << 2; i < E; ++i) hit(dst[i], i);
    } else {
        for (int k = 0; k < 4; ++k) {
            int i = gtid * 4 + k;
            if (i < E) hit(dst[i], i);
        }
    }
}

// ---------------------------------------------------------------------------
// scan2: level-2 collection (dst marked M2) + self-prop F2 -> F1; zeroes
// AGG1 rows at F1-insert time.
// ---------------------------------------------------------------------------
__global__ void k_scan2(const int* __restrict__ src, const int* __restrict__ dst,
                        int E, int* __restrict__ mark, int* __restrict__ cnt,
                        const int* __restrict__ F2, int* __restrict__ F1,
                        int2* __restrict__ E2l, float* __restrict__ AGG1)
{
    const int gtid = blockIdx.x * blockDim.x + threadIdx.x;

    {   // self-prop: every F2 member enters F1
        int sc = cnt[0]; if (sc > CAP_F2) sc = CAP_F2;
        if (gtid < sc) {
            int v = F2[gtid];
            if (!(atomicOr(&mark[v], M1) & M1)) {
                int p = atomicAdd(&cnt[2], 1);
                if (p < CAP_F1) F1[p] = v;
                zero_row(AGG1, v);
            }
        }
    }

    auto hit = [&](int d, int i) {
        if (mark[d] & M2) {
            int s = src[i];
            int p = atomicAdd(&cnt[3], 1);
            if (p < CAP_E2) E2l[p] = make_int2(s, d);
            if (!(atomicOr(&mark[s], M1) & M1)) {
                int q = atomicAdd(&cnt[2], 1);
                if (q < CAP_F1) F1[q] = s;
                zero_row(AGG1, s);
            }
        }
    };

    const int nq = E >> 2;
    if ((((uintptr_t)dst) & 15) == 0) {
        if (gtid < nq) {
            int4 d4 = ((const int4*)dst)[gtid];
            int i = gtid << 2;
            hit(d4.x, i); hit(d4.y, i + 1); hit(d4.z, i + 2); hit(d4.w, i + 3);
        }
        if (gtid == 0)
            for (int i = nq << 2; i < E; ++i) hit(dst[i], i);
    } else {
        for (int k = 0; k < 4; ++k) {
            int i = gtid * 4 + k;
            if (i < E) hit(dst[i], i);
        }
    }
}

// ---------------------------------------------------------------------------
// k_l1: fused level-3 detect + layer-1 GEMV scatter.
//   (a) F1 self contributions: AGG1[v] += (1/(1+deg[v])) * x[v]@W1
//   (b) edge scan: dst marked M1 -> AGG1[d] += dinv[s]*dinv[d] * x[s]@W1
// ---------------------------------------------------------------------------
__global__ __launch_bounds__(256) void k_l1(
    const int* __restrict__ src, const int* __restrict__ dst, int E,
    const int* __restrict__ mark, const int* __restrict__ deg,
    const int* __restrict__ cnt, const int* __restrict__ F1,
    const float* __restrict__ x, const float* __restrict__ W1,
    float* __restrict__ AGG1)
{
    __shared__ float wsm[128][128];
    const int t = threadIdx.x;
    {   // stage W1
        const float4* W4 = (const float4*)W1;
        float4* S4 = (float4*)&wsm[0][0];
        #pragma unroll
        for (int it = 0; it < 16; ++it) S4[it * 256 + t] = W4[it * 256 + t];
    }
    __syncthreads();

    const int wave = t >> 6, lane = t & 63;
    const int wg = blockIdx.x * 4 + wave;      // global wave id
    const int nw = gridDim.x * 4;

    // (a) self contributions from F1 list
    int f1 = cnt[2]; if (f1 > CAP_F1) f1 = CAP_F1;
    for (int idx = wg; idx < f1; idx += nw) {
        int v = F1[idx];
        float w = 1.f / (1.f + (float)deg[v]);   // dinv[v]^2
        gemv_scatter(x, v, w, v, wsm, lane, AGG1);
    }

    // (b) edge scan: 4 edges per lane per round, ballot the rare hits
    const int nq = E >> 2;
    const int4* d4p = (const int4*)dst;
    const bool vec4 = ((((uintptr_t)dst) & 15) == 0);
    if (vec4) {
        for (int q0 = wg * 64; q0 < nq; q0 += nw * 64) {
            int q = q0 + lane;
            int4 d4 = make_int4(-1, -1, -1, -1);
            if (q < nq) d4 = d4p[q];
            #pragma unroll
            for (int sub = 0; sub < 4; ++sub) {
                int d = (sub == 0) ? d4.x : (sub == 1) ? d4.y : (sub == 2) ? d4.z : d4.w;
                bool hit = false; int s = 0;
                if (q < nq) {
                    hit = (mark[d] & M1) != 0;
                    if (hit) s = src[(q << 2) + sub];
                }
                unsigned long long m = __ballot(hit);
                while (m) {
                    int j = __ffsll(m) - 1; m &= m - 1;
                    int sb = __shfl(s, j), db = __shfl(d, j);
                    float w = rsqrtf(1.f + (float)deg[sb]) * rsqrtf(1.f + (float)deg[db]);
                    gemv_scatter(x, sb, w, db, wsm, lane, AGG1);
                }
            }
        }
        // remainder edges: wave 0 of block 0, cooperative
        if (blockIdx.x == 0 && wave == 0) {
            for (int i = nq << 2; i < E; ++i) {
                int d = dst[i];
                if (mark[d] & M1) {
                    int s = src[i];
                    float w = rsqrtf(1.f + (float)deg[s]) * rsqrtf(1.f + (float)deg[d]);
                    gemv_scatter(x, s, w, d, wsm, lane, AGG1);
                }
            }
        }
    } else {
        for (int i0 = wg * 64; i0 < E; i0 += nw * 64) {
            int i = i0 + lane;
            bool hit = false; int s = 0, d = -1;
            if (i < E) {
                d = dst[i];
                hit = (mark[d] & M1) != 0;
                if (hit) s = src[i];
            }
            unsigned long long m = __ballot(hit);
            while (m) {
                int j = __ffsll(m) - 1; m &= m - 1;
                int sb = __shfl(s, j), db = __shfl(d, j);
                float w = rsqrtf(1.f + (float)deg[sb]) * rsqrtf(1.f + (float)deg[db]);
                gemv_scatter(x, sb, w, db, wsm, lane, AGG1);
            }
        }
    }
}

// ---------------------------------------------------------------------------
// k_l2tail (1 block x 1024): layer-2 GEMV over E2 into AGG2, then layer-3
// over E3 with register accumulate (all dst == last), relu+bias, FC.
// ---------------------------------------------------------------------------
__global__ __launch_bounds__(1024) void k_l2tail(
    const int2* __restrict__ E2l, const int2* __restrict__ E3l,
    const int* __restrict__ cnt,
    const float* __restrict__ AGG1, const float* __restrict__ b1,
    const float* __restrict__ W2, const float* __restrict__ b2,
    const float* __restrict__ W3, const float* __restrict__ b3,
    const float* __restrict__ fcW, const float* __restrict__ fcb,
    const int* __restrict__ deg, int last,
    float* __restrict__ AGG2, float* __restrict__ out)
{
    __shared__ float wsm[128][128];
    const int t = threadIdx.x;
    const int wave = t >> 6, lane = t & 63;    // 16 waves

    {   // stage W2 (4096 float4 / 1024 thr = 4 each)
        const float4* W4 = (const float4*)W2;
        float4* S4 = (float4*)&wsm[0][0];
        #pragma unroll
        for (int it = 0; it < 4; ++it) S4[it * 1024 + t] = W4[it * 1024 + t];
    }
    __syncthreads();

    // layer 2: per-E2-edge GEMV scatter into AGG2
    int e2 = cnt[3]; if (e2 > CAP_E2) e2 = CAP_E2;
    for (int e = wave; e < e2; e += 16) {
        int2 ed = E2l[e];
        float w = rsqrtf(1.f + (float)deg[ed.x]) * rsqrtf(1.f + (float)deg[ed.y]);
        size_t so = (size_t)ed.x * NF;
        float x0 = fmaxf(AGG1[so + lane]      + b1[lane],      0.f);
        float x1 = fmaxf(AGG1[so + lane + 64] + b1[lane + 64], 0.f);
        float a0 = 0.f, a1 = 0.f;
        #pragma unroll 16
        for (int k = 0; k < 64; ++k) {
            float xk = __shfl(x0, k);
            a0 += xk * wsm[k][lane];
            a1 += xk * wsm[k][lane + 64];
        }
        #pragma unroll 16
        for (int k = 0; k < 64; ++k) {
            float xk = __shfl(x1, k);
            a0 += xk * wsm[k + 64][lane];
            a1 += xk * wsm[k + 64][lane + 64];
        }
        size_t off = (size_t)ed.y * NF;
        atomicAdd(&AGG2[off + lane],      w * a0);
        atomicAdd(&AGG2[off + lane + 64], w * a1);
    }
    __threadfence();      // make atomics visible to this block's normal loads
    __syncthreads();

    {   // stage W3 (reuse LDS)
        const float4* W4 = (const float4*)W3;
        float4* S4 = (float4*)&wsm[0][0];
        #pragma unroll
        for (int it = 0; it < 4; ++it) S4[it * 1024 + t] = W4[it * 1024 + t];
    }
    __syncthreads();

    // layer 3: per-E3-edge GEMV, register accumulate (all dst == last)
    int e3 = cnt[1]; if (e3 > CAP_E3) e3 = CAP_E3;
    const float dl = rsqrtf(1.f + (float)deg[last]);
    float acc0 = 0.f, acc1 = 0.f;
    for (int e = wave; e < e3; e += 16) {
        int s = E3l[e].x;
        float w = rsqrtf(1.f + (float)deg[s]) * dl;
        size_t so = (size_t)s * NF;
        float x0 = fmaxf(AGG2[so + lane]      + b2[lane],      0.f);
        float x1 = fmaxf(AGG2[so + lane + 64] + b2[lane + 64], 0.f);
        float a0 = 0.f, a1 = 0.f;
        #pragma unroll 16
        for (int k = 0; k < 64; ++k) {
            float xk = __shfl(x0, k);
            a0 += xk * wsm[k][lane];
            a1 += xk * wsm[k][lane + 64];
        }
        #pragma unroll 16
        for (int k = 0; k < 64; ++k) {
            float xk = __shfl(x1, k);
            a0 += xk * wsm[k + 64][lane];
            a1 += xk * wsm[k + 64][lane + 64];
        }
        acc0 += w * a0;
        acc1 += w * a1;
    }
    __syncthreads();                     // all waves done reading W3
    wsm[wave][lane]      = acc0;         // rows 0..15 as reduce buffer
    wsm[wave][lane + 64] = acc1;
    __syncthreads();
    if (t < NF) {
        float s = 0.f;
        #pragma unroll
        for (int k = 0; k < 16; ++k) s += wsm[k][t];
        wsm[16][t] = fmaxf(s + b3[t], 0.f);
    }
    __syncthreads();
    if (t < OUTF) {
        float acc = fcb[t];
        #pragma unroll 16
        for (int k = 0; k < NF; ++k) acc += wsm[16][k] * fcW[k * OUTF + t];
        out[t] = acc;
    }
}

// ---------------------------------------------------------------------------

extern "C" void kernel_launch(void* const* d_in, const int* in_sizes, int n_in,
                              void* d_out, int out_size, void* d_ws, size_t ws_size,
                              hipStream_t stream)
{
    const float* x    = (const float*)d_in[0];
    const int*   ei   = (const int*)d_in[1];
    const float* W1   = (const float*)d_in[2];
    const float* b1   = (const float*)d_in[3];
    const float* W2   = (const float*)d_in[4];
    const float* b2   = (const float*)d_in[5];
    const float* W3   = (const float*)d_in[6];
    const float* b3   = (const float*)d_in[7];
    const float* fcW  = (const float*)d_in[8];
    const float* fcb  = (const float*)d_in[9];
    float* out = (float*)d_out;

    const int n = in_sizes[0] / NF;       // 50000
    const int E = in_sizes[1] / 2;        // 600000
    const int* src = ei;
    const int* dst = ei + E;
    const int last = n - 1;

    char* wp = (char*)d_ws;
    auto alloc = [&](size_t bytes) -> void* {
        void* r = (void*)wp;
        wp += (bytes + 255) & ~(size_t)255;
        return r;
    };
    // zeroed region: deg | mark | cnt  (one memset, ~400KB)
    int*   deg  = (int*)alloc((size_t)n * 4);
    int*   mark = (int*)alloc((size_t)n * 4);
    int*   cnt  = (int*)alloc(64 * 4);
    size_t zbytes = (char*)wp - (char*)deg;

    int*   F2   = (int*) alloc(CAP_F2 * 4);
    int2*  E3   = (int2*)alloc(CAP_E3 * 8);
    int*   F1   = (int*) alloc(CAP_F1 * 4);
    int2*  E2   = (int2*)alloc(CAP_E2 * 8);
    float* AGG1 = (float*)alloc((size_t)n * NF * 4);
    float* AGG2 = (float*)alloc((size_t)n * NF * 4);

    hipMemsetAsync(deg, 0, zbytes, stream);

    const int B = 256;
    const int SB = ((E + 3) / 4 + B - 1) / B;

    k_scan1<<<SB, B, 0, stream>>>(src, dst, E, last, mark, deg, cnt, F2, E3, E2, AGG2);
    k_scan2<<<SB, B, 0, stream>>>(src, dst, E, mark, cnt, F2, F1, E2, AGG1);
    k_l1   <<<256, B, 0, stream>>>(src, dst, E, mark, deg, cnt, F1, x, W1, AGG1);
    k_l2tail<<<1, 1024, 0, stream>>>(E2, E3, cnt, AGG1, b1, W2, b2, W3, b3,
                                     fcW, fcb, deg, last, AGG2, out);
}

// Round 11
// 162.225 us; speedup vs baseline: 1.4314x; 1.4314x over previous
//
#include <hip/hip_runtime.h>

#define NF 128
#define OUTF 64

// mark bits
#define M2 1   // layer-2 frontier (in-neighbors of last, + last)
#define M1 2   // layer-1 frontier

// capacity caps (expected ~13 / ~190 / ~2600; huge slack)
#define CAP_F2 2048
#define CAP_E3 4096
#define CAP_F1 32768
#define CAP_E2 65536

// cnt[0]=F2, cnt[1]=E3, cnt[2]=F1, cnt[3]=E2

__device__ __forceinline__ void zero_row(float* A, int v) {
    float4* r = (float4*)(A + (size_t)v * NF);
    #pragma unroll
    for (int k = 0; k < 32; ++k) r[k] = make_float4(0.f, 0.f, 0.f, 0.f);
}

// wave-cooperative GEMV + scatter: AGG[d] += w * (xrow(s) @ W[LDS])
__device__ __forceinline__ void gemv_scatter(
    const float* __restrict__ Xin, int s, float w, int d,
    float (&wsm)[128][128], int lane, float* __restrict__ AGG)
{
    size_t so = (size_t)s * NF;
    float x0 = Xin[so + lane];
    float x1 = Xin[so + lane + 64];
    float a0 = 0.f, a1 = 0.f;
    #pragma unroll 16
    for (int k = 0; k < 64; ++k) {
        float xk = __shfl(x0, k);
        a0 += xk * wsm[k][lane];
        a1 += xk * wsm[k][lane + 64];
    }
    #pragma unroll 16
    for (int k = 0; k < 64; ++k) {
        float xk = __shfl(x1, k);
        a0 += xk * wsm[k + 64][lane];
        a1 += xk * wsm[k + 64][lane + 64];
    }
    size_t off = (size_t)d * NF;
    atomicAdd(&AGG[off + lane],      w * a0);
    atomicAdd(&AGG[off + lane + 64], w * a1);
}

// ---------------------------------------------------------------------------
// scan1: unconditional in-degree + level-1 (dst == last) + seed; zeroes
// AGG2 rows at F2-insert time.
// ---------------------------------------------------------------------------
__global__ void k_scan1(const int* __restrict__ src, const int* __restrict__ dst,
                        int E, int last, int* __restrict__ mark, int* __restrict__ deg,
                        int* __restrict__ cnt, int* __restrict__ F2,
                        int2* __restrict__ E3l, int2* __restrict__ E2l,
                        float* __restrict__ AGG2)
{
    const int gtid = blockIdx.x * blockDim.x + threadIdx.x;
    if (gtid == 0) {
        atomicOr(&mark[last], M2);
        int q = atomicAdd(&cnt[0], 1);
        if (q < CAP_F2) F2[q] = last;
        zero_row(AGG2, last);
        int r = atomicAdd(&cnt[3], 1);                 // self-loop edge in E2
        if (r < CAP_E2) E2l[r] = make_int2(last, last);
        int e = atomicAdd(&cnt[1], 1);                 // self-loop edge in E3
        if (e < CAP_E3) E3l[e] = make_int2(last, last);
    }

    auto hit = [&](int d, int i) {
        atomicAdd(&deg[d], 1);                         // in-degree, all nodes
        if (d == last) {
            int s = src[i];
            int p = atomicAdd(&cnt[1], 1);
            if (p < CAP_E3) E3l[p] = make_int2(s, d);
            if (s != last && !(atomicOr(&mark[s], M2) & M2)) {
                int q = atomicAdd(&cnt[0], 1);
                if (q < CAP_F2) F2[q] = s;
                zero_row(AGG2, s);
                int r = atomicAdd(&cnt[3], 1);         // self-loop edge in E2
                if (r < CAP_E2) E2l[r] = make_int2(s, s);
            }
        }
    };

    const int nq = E >> 2;
    if ((((uintptr_t)dst) & 15) == 0) {
        if (gtid < nq) {
            int4 d4 = ((const int4*)dst)[gtid];
            int i = gtid << 2;
            hit(d4.x, i); hit(d4.y, i + 1); hit(d4.z, i + 2); hit(d4.w, i + 3);
        }
        if (gtid == 0)
            for (int i = nq << 2; i < E; ++i) hit(dst[i], i);
    } else {
        for (int k = 0; k < 4; ++k) {
            int i = gtid * 4 + k;
            if (i < E) hit(dst[i], i);
        }
    }
}

// ---------------------------------------------------------------------------
// scan2: level-2 collection (dst marked M2) + self-prop F2 -> F1; zeroes
// AGG1 rows at F1-insert time.
// ---------------------------------------------------------------------------
__global__ void k_scan2(const int* __restrict__ src, const int* __restrict__ dst,
                        int E, int* __restrict__ mark, int* __restrict__ cnt,
                        const int* __restrict__ F2, int* __restrict__ F1,
                        int2* __restrict__ E2l, float* __restrict__ AGG1)
{
    const int gtid = blockIdx.x * blockDim.x + threadIdx.x;

    {   // self-prop: every F2 member enters F1
        int sc = cnt[0]; if (sc > CAP_F2) sc = CAP_F2;
        if (gtid < sc) {
            int v = F2[gtid];
            if (!(atomicOr(&mark[v], M1) & M1)) {
                int p = atomicAdd(&cnt[2], 1);
                if (p < CAP_F1) F1[p] = v;
                zero_row(AGG1, v);
            }
        }
    }

    auto hit = [&](int d, int i) {
        if (mark[d] & M2) {
            int s = src[i];
            int p = atomicAdd(&cnt[3], 1);
            if (p < CAP_E2) E2l[p] = make_int2(s, d);
            if (!(atomicOr(&mark[s], M1) & M1)) {
                int q = atomicAdd(&cnt[2], 1);
                if (q < CAP_F1) F1[q] = s;
                zero_row(AGG1, s);
            }
        }
    };

    const int nq = E >> 2;
    if ((((uintptr_t)dst) & 15) == 0) {
        if (gtid < nq) {
            int4 d4 = ((const int4*)dst)[gtid];
            int i = gtid << 2;
            hit(d4.x, i); hit(d4.y, i + 1); hit(d4.z, i + 2); hit(d4.w, i + 3);
        }
        if (gtid == 0)
            for (int i = nq << 2; i < E; ++i) hit(dst[i], i);
    } else {
        for (int k = 0; k < 4; ++k) {
            int i = gtid * 4 + k;
            if (i < E) hit(dst[i], i);
        }
    }
}

// ---------------------------------------------------------------------------
// k_l1: fused level-3 detect + layer-1 GEMV scatter (proven in r10).
//   (a) F1 self contributions: AGG1[v] += (1/(1+deg[v])) * x[v]@W1
//   (b) edge scan: dst marked M1 -> AGG1[d] += dinv[s]*dinv[d] * x[s]@W1
// ---------------------------------------------------------------------------
__global__ __launch_bounds__(256) void k_l1(
    const int* __restrict__ src, const int* __restrict__ dst, int E,
    const int* __restrict__ mark, const int* __restrict__ deg,
    const int* __restrict__ cnt, const int* __restrict__ F1,
    const float* __restrict__ x, const float* __restrict__ W1,
    float* __restrict__ AGG1)
{
    __shared__ float wsm[128][128];
    const int t = threadIdx.x;
    {   // stage W1
        const float4* W4 = (const float4*)W1;
        float4* S4 = (float4*)&wsm[0][0];
        #pragma unroll
        for (int it = 0; it < 16; ++it) S4[it * 256 + t] = W4[it * 256 + t];
    }
    __syncthreads();

    const int wave = t >> 6, lane = t & 63;
    const int wg = blockIdx.x * 4 + wave;      // global wave id
    const int nw = gridDim.x * 4;

    // (a) self contributions from F1 list
    int f1 = cnt[2]; if (f1 > CAP_F1) f1 = CAP_F1;
    for (int idx = wg; idx < f1; idx += nw) {
        int v = F1[idx];
        float w = 1.f / (1.f + (float)deg[v]);   // dinv[v]^2
        gemv_scatter(x, v, w, v, wsm, lane, AGG1);
    }

    // (b) edge scan: 4 edges per lane per round, ballot the rare hits
    const int nq = E >> 2;
    const int4* d4p = (const int4*)dst;
    const bool vec4 = ((((uintptr_t)dst) & 15) == 0);
    if (vec4) {
        for (int q0 = wg * 64; q0 < nq; q0 += nw * 64) {
            int q = q0 + lane;
            int4 d4 = make_int4(-1, -1, -1, -1);
            if (q < nq) d4 = d4p[q];
            #pragma unroll
            for (int sub = 0; sub < 4; ++sub) {
                int d = (sub == 0) ? d4.x : (sub == 1) ? d4.y : (sub == 2) ? d4.z : d4.w;
                bool hit = false; int s = 0;
                if (q < nq) {
                    hit = (mark[d] & M1) != 0;
                    if (hit) s = src[(q << 2) + sub];
                }
                unsigned long long m = __ballot(hit);
                while (m) {
                    int j = __ffsll(m) - 1; m &= m - 1;
                    int sb = __shfl(s, j), db = __shfl(d, j);
                    float w = rsqrtf(1.f + (float)deg[sb]) * rsqrtf(1.f + (float)deg[db]);
                    gemv_scatter(x, sb, w, db, wsm, lane, AGG1);
                }
            }
        }
        if (blockIdx.x == 0 && wave == 0) {
            for (int i = nq << 2; i < E; ++i) {
                int d = dst[i];
                if (mark[d] & M1) {
                    int s = src[i];
                    float w = rsqrtf(1.f + (float)deg[s]) * rsqrtf(1.f + (float)deg[d]);
                    gemv_scatter(x, s, w, d, wsm, lane, AGG1);
                }
            }
        }
    } else {
        for (int i0 = wg * 64; i0 < E; i0 += nw * 64) {
            int i = i0 + lane;
            bool hit = false; int s = 0, d = -1;
            if (i < E) {
                d = dst[i];
                hit = (mark[d] & M1) != 0;
                if (hit) s = src[i];
            }
            unsigned long long m = __ballot(hit);
            while (m) {
                int j = __ffsll(m) - 1; m &= m - 1;
                int sb = __shfl(s, j), db = __shfl(d, j);
                float w = rsqrtf(1.f + (float)deg[sb]) * rsqrtf(1.f + (float)deg[db]);
                gemv_scatter(x, sb, w, db, wsm, lane, AGG1);
            }
        }
    }
}

// ---------------------------------------------------------------------------
// layer-2: per-edge GEMV + atomic scatter, MULTI-BLOCK (r9 proven; r10's
// single-block fusion was LDS-BW-bound on one CU at 93us).
// AGG2[d] += w * (relu(AGG1[s]+b1) @ W2)
// ---------------------------------------------------------------------------
__global__ __launch_bounds__(256) void k_gemv2(
    const int2* __restrict__ Elist, const int* __restrict__ cntPtr, int cap,
    const float* __restrict__ AGG1, const float* __restrict__ b1,
    const float* __restrict__ W2, const int* __restrict__ deg,
    float* __restrict__ AGG2)
{
    __shared__ float wsm[128][128];
    int ecnt = *cntPtr; if (ecnt > cap) ecnt = cap;
    if ((int)blockIdx.x * 4 >= ecnt) return;      // block-uniform: no work

    const int t = threadIdx.x;
    {   // stage W2
        const float4* W4 = (const float4*)W2;
        float4* S4 = (float4*)&wsm[0][0];
        #pragma unroll
        for (int it = 0; it < 16; ++it) S4[it * 256 + t] = W4[it * 256 + t];
    }
    __syncthreads();

    const int wave = t >> 6, lane = t & 63;
    const int wstride = gridDim.x * 4;
    for (int e = blockIdx.x * 4 + wave; e < ecnt; e += wstride) {
        int2 ed = Elist[e];
        float w = rsqrtf(1.f + (float)deg[ed.x]) * rsqrtf(1.f + (float)deg[ed.y]);
        size_t so = (size_t)ed.x * NF;
        float x0 = fmaxf(AGG1[so + lane]      + b1[lane],      0.f);
        float x1 = fmaxf(AGG1[so + lane + 64] + b1[lane + 64], 0.f);
        float a0 = 0.f, a1 = 0.f;
        #pragma unroll 16
        for (int k = 0; k < 64; ++k) {
            float xk = __shfl(x0, k);
            a0 += xk * wsm[k][lane];
            a1 += xk * wsm[k][lane + 64];
        }
        #pragma unroll 16
        for (int k = 0; k < 64; ++k) {
            float xk = __shfl(x1, k);
            a0 += xk * wsm[k + 64][lane];
            a1 += xk * wsm[k + 64][lane + 64];
        }
        size_t off = (size_t)ed.y * NF;
        atomicAdd(&AGG2[off + lane],      w * a0);
        atomicAdd(&AGG2[off + lane + 64], w * a1);
    }
}

// ---------------------------------------------------------------------------
// tail (1 block x 256): ~13 E3 GEMVs with register accumulate, relu+b3, FC.
// ---------------------------------------------------------------------------
__global__ __launch_bounds__(256) void k_tail(
    const int2* __restrict__ E3l, const int* __restrict__ cntPtr, int cap,
    const float* __restrict__ AGG2, const float* __restrict__ b2,
    const float* __restrict__ W3, const float* __restrict__ b3,
    const float* __restrict__ fcW, const float* __restrict__ fcb,
    const int* __restrict__ deg, int last, float* __restrict__ out)
{
    __shared__ float wsm[128][128];
    const int t = threadIdx.x;
    {   // stage W3
        const float4* W4 = (const float4*)W3;
        float4* S4 = (float4*)&wsm[0][0];
        #pragma unroll
        for (int it = 0; it < 16; ++it) S4[it * 256 + t] = W4[it * 256 + t];
    }
    __syncthreads();

    const int wave = t >> 6, lane = t & 63;
    int e3 = *cntPtr; if (e3 > cap) e3 = cap;
    const float dl = rsqrtf(1.f + (float)deg[last]);

    float acc0 = 0.f, acc1 = 0.f;
    for (int e = wave; e < e3; e += 4) {
        int s = E3l[e].x;
        float w = rsqrtf(1.f + (float)deg[s]) * dl;
        size_t so = (size_t)s * NF;
        float x0 = fmaxf(AGG2[so + lane]      + b2[lane],      0.f);
        float x1 = fmaxf(AGG2[so + lane + 64] + b2[lane + 64], 0.f);
        float a0 = 0.f, a1 = 0.f;
        #pragma unroll 16
        for (int k = 0; k < 64; ++k) {
            float xk = __shfl(x0, k);
            a0 += xk * wsm[k][lane];
            a1 += xk * wsm[k][lane + 64];
        }
        #pragma unroll 16
        for (int k = 0; k < 64; ++k) {
            float xk = __shfl(x1, k);
            a0 += xk * wsm[k + 64][lane];
            a1 += xk * wsm[k + 64][lane + 64];
        }
        acc0 += w * a0;
        acc1 += w * a1;
    }
    __syncthreads();                     // all waves done reading W3
    wsm[wave][lane]      = acc0;         // reuse rows 0..3 as reduce buffer
    wsm[wave][lane + 64] = acc1;
    __syncthreads();
    if (t < NF) {
        float s4 = wsm[0][t] + wsm[1][t] + wsm[2][t] + wsm[3][t];
        wsm[8][t] = fmaxf(s4 + b3[t], 0.f);
    }
    __syncthreads();
    if (t < OUTF) {
        float acc = fcb[t];
        #pragma unroll 16
        for (int k = 0; k < NF; ++k) acc += wsm[8][k] * fcW[k * OUTF + t];
        out[t] = acc;
    }
}

// ---------------------------------------------------------------------------

extern "C" void kernel_launch(void* const* d_in, const int* in_sizes, int n_in,
                              void* d_out, int out_size, void* d_ws, size_t ws_size,
                              hipStream_t stream)
{
    const float* x    = (const float*)d_in[0];
    const int*   ei   = (const int*)d_in[1];
    const float* W1   = (const float*)d_in[2];
    const float* b1   = (const float*)d_in[3];
    const float* W2   = (const float*)d_in[4];
    const float* b2   = (const float*)d_in[5];
    const float* W3   = (const float*)d_in[6];
    const float* b3   = (const float*)d_in[7];
    const float* fcW  = (const float*)d_in[8];
    const float* fcb  = (const float*)d_in[9];
    float* out = (float*)d_out;

    const int n = in_sizes[0] / NF;       // 50000
    const int E = in_sizes[1] / 2;        // 600000
    const int* src = ei;
    const int* dst = ei + E;
    const int last = n - 1;

    char* wp = (char*)d_ws;
    auto alloc = [&](size_t bytes) -> void* {
        void* r = (void*)wp;
        wp += (bytes + 255) & ~(size_t)255;
        return r;
    };
    // zeroed region: deg | mark | cnt  (one memset, ~400KB)
    int*   deg  = (int*)alloc((size_t)n * 4);
    int*   mark = (int*)alloc((size_t)n * 4);
    int*   cnt  = (int*)alloc(64 * 4);
    size_t zbytes = (char*)wp - (char*)deg;

    int*   F2   = (int*) alloc(CAP_F2 * 4);
    int2*  E3   = (int2*)alloc(CAP_E3 * 8);
    int*   F1   = (int*) alloc(CAP_F1 * 4);
    int2*  E2   = (int2*)alloc(CAP_E2 * 8);
    float* AGG1 = (float*)alloc((size_t)n * NF * 4);
    float* AGG2 = (float*)alloc((size_t)n * NF * 4);

    hipMemsetAsync(deg, 0, zbytes, stream);

    const int B = 256;
    const int SB = ((E + 3) / 4 + B - 1) / B;

    k_scan1<<<SB, B, 0, stream>>>(src, dst, E, last, mark, deg, cnt, F2, E3, E2, AGG2);
    k_scan2<<<SB, B, 0, stream>>>(src, dst, E, mark, cnt, F2, F1, E2, AGG1);
    k_l1   <<<256, B, 0, stream>>>(src, dst, E, mark, deg, cnt, F1, x, W1, AGG1);
    k_gemv2<<<64,  B, 0, stream>>>(E2, &cnt[3], CAP_E2, AGG1, b1, W2, deg, AGG2);
    k_tail <<<1,   B, 0, stream>>>(E3, &cnt[1], CAP_E3, AGG2, b2, W3, b3,
                                   fcW, fcb, deg, last, out);
}

// Round 12
// 159.388 us; speedup vs baseline: 1.4569x; 1.0178x over previous
//
#include <hip/hip_runtime.h>

#define NF 128
#define OUTF 64

// dm[v]: bit0 = M2 mark, bit1 = M1 mark, bits>=3 = in-degree count
#define M2 1
#define M1 2
#define DEG_SHIFT 3
#define DEG_INC 8

// capacity caps (expected ~13 / ~190 / ~2600; huge slack)
#define CAP_F2 2048
#define CAP_E3 4096
#define CAP_F1 32768
#define CAP_E2 65536

// cnt[0]=F2, cnt[1]=E3, cnt[2]=F1, cnt[3]=E2, cnt[8]=gemv2 done-counter

__device__ __forceinline__ float degw(int dmv) {      // dinv from dm word
    return rsqrtf(1.f + (float)(dmv >> DEG_SHIFT));
}

__device__ __forceinline__ void zero_row(float* A, int v) {
    float4* r = (float4*)(A + (size_t)v * NF);
    #pragma unroll
    for (int k = 0; k < 32; ++k) r[k] = make_float4(0.f, 0.f, 0.f, 0.f);
}

// wave-cooperative GEMV + scatter: AGG[d] += w * (xrow(s) @ W[LDS])
__device__ __forceinline__ void gemv_scatter(
    const float* __restrict__ Xin, int s, float w, int d,
    float (&wsm)[128][128], int lane, float* __restrict__ AGG)
{
    size_t so = (size_t)s * NF;
    float x0 = Xin[so + lane];
    float x1 = Xin[so + lane + 64];
    float a0 = 0.f, a1 = 0.f;
    #pragma unroll 16
    for (int k = 0; k < 64; ++k) {
        float xk = __shfl(x0, k);
        a0 += xk * wsm[k][lane];
        a1 += xk * wsm[k][lane + 64];
    }
    #pragma unroll 16
    for (int k = 0; k < 64; ++k) {
        float xk = __shfl(x1, k);
        a0 += xk * wsm[k + 64][lane];
        a1 += xk * wsm[k + 64][lane + 64];
    }
    size_t off = (size_t)d * NF;
    atomicAdd(&AGG[off + lane],      w * a0);
    atomicAdd(&AGG[off + lane + 64], w * a1);
}

// ---------------------------------------------------------------------------
// scan1: unconditional in-degree (dm += 8) + level-1 (dst == last) + seed;
// zeroes AGG2 rows at F2-insert time.
// ---------------------------------------------------------------------------
__global__ void k_scan1(const int* __restrict__ src, const int* __restrict__ dst,
                        int E, int last, int* __restrict__ dm,
                        int* __restrict__ cnt, int* __restrict__ F2,
                        int2* __restrict__ E3l, int2* __restrict__ E2l,
                        float* __restrict__ AGG2)
{
    const int gtid = blockIdx.x * blockDim.x + threadIdx.x;
    if (gtid == 0) {
        atomicOr(&dm[last], M2);
        int q = atomicAdd(&cnt[0], 1);
        if (q < CAP_F2) F2[q] = last;
        zero_row(AGG2, last);
        int r = atomicAdd(&cnt[3], 1);                 // self-loop edge in E2
        if (r < CAP_E2) E2l[r] = make_int2(last, last);
        int e = atomicAdd(&cnt[1], 1);                 // self-loop edge in E3
        if (e < CAP_E3) E3l[e] = make_int2(last, last);
    }

    auto hit = [&](int d, int i) {
        atomicAdd(&dm[d], DEG_INC);                    // in-degree, all nodes
        if (d == last) {
            int s = src[i];
            int p = atomicAdd(&cnt[1], 1);
            if (p < CAP_E3) E3l[p] = make_int2(s, d);
            if (s != last && !(atomicOr(&dm[s], M2) & M2)) {
                int q = atomicAdd(&cnt[0], 1);
                if (q < CAP_F2) F2[q] = s;
                zero_row(AGG2, s);
                int r = atomicAdd(&cnt[3], 1);         // self-loop edge in E2
                if (r < CAP_E2) E2l[r] = make_int2(s, s);
            }
        }
    };

    const int nq = E >> 2;
    if ((((uintptr_t)dst) & 15) == 0) {
        if (gtid < nq) {
            int4 d4 = ((const int4*)dst)[gtid];
            int i = gtid << 2;
            hit(d4.x, i); hit(d4.y, i + 1); hit(d4.z, i + 2); hit(d4.w, i + 3);
        }
        if (gtid == 0)
            for (int i = nq << 2; i < E; ++i) hit(dst[i], i);
    } else {
        for (int k = 0; k < 4; ++k) {
            int i = gtid * 4 + k;
            if (i < E) hit(dst[i], i);
        }
    }
}

// ---------------------------------------------------------------------------
// scan2: level-2 collection (dst marked M2) + self-prop F2 -> F1; zeroes
// AGG1 rows at F1-insert time.
// ---------------------------------------------------------------------------
__global__ void k_scan2(const int* __restrict__ src, const int* __restrict__ dst,
                        int E, int* __restrict__ dm, int* __restrict__ cnt,
                        const int* __restrict__ F2, int* __restrict__ F1,
                        int2* __restrict__ E2l, float* __restrict__ AGG1)
{
    const int gtid = blockIdx.x * blockDim.x + threadIdx.x;

    {   // self-prop: every F2 member enters F1
        int sc = cnt[0]; if (sc > CAP_F2) sc = CAP_F2;
        if (gtid < sc) {
            int v = F2[gtid];
            if (!(atomicOr(&dm[v], M1) & M1)) {
                int p = atomicAdd(&cnt[2], 1);
                if (p < CAP_F1) F1[p] = v;
                zero_row(AGG1, v);
            }
        }
    }

    auto hit = [&](int d, int i) {
        if (dm[d] & M2) {
            int s = src[i];
            int p = atomicAdd(&cnt[3], 1);
            if (p < CAP_E2) E2l[p] = make_int2(s, d);
            if (!(atomicOr(&dm[s], M1) & M1)) {
                int q = atomicAdd(&cnt[2], 1);
                if (q < CAP_F1) F1[q] = s;
                zero_row(AGG1, s);
            }
        }
    };

    const int nq = E >> 2;
    if ((((uintptr_t)dst) & 15) == 0) {
        if (gtid < nq) {
            int4 d4 = ((const int4*)dst)[gtid];
            int i = gtid << 2;
            hit(d4.x, i); hit(d4.y, i + 1); hit(d4.z, i + 2); hit(d4.w, i + 3);
        }
        if (gtid == 0)
            for (int i = nq << 2; i < E; ++i) hit(dst[i], i);
    } else {
        for (int k = 0; k < 4; ++k) {
            int i = gtid * 4 + k;
            if (i < E) hit(dst[i], i);
        }
    }
}

// ---------------------------------------------------------------------------
// k_l1: fused level-3 detect + layer-1 GEMV scatter.
//   (a) F1 self contributions: AGG1[v] += (1/(1+deg[v])) * x[v]@W1
//   (b) edge scan: dst marked M1 -> AGG1[d] += dinv[s]*dinv[d] * x[s]@W1
// dm[d] probe doubles as the degree source (shfl'd to the scatter).
// ---------------------------------------------------------------------------
__global__ __launch_bounds__(256) void k_l1(
    const int* __restrict__ src, const int* __restrict__ dst, int E,
    const int* __restrict__ dm, const int* __restrict__ cnt,
    const int* __restrict__ F1,
    const float* __restrict__ x, const float* __restrict__ W1,
    float* __restrict__ AGG1)
{
    __shared__ float wsm[128][128];
    const int t = threadIdx.x;
    {   // stage W1
        const float4* W4 = (const float4*)W1;
        float4* S4 = (float4*)&wsm[0][0];
        #pragma unroll
        for (int it = 0; it < 16; ++it) S4[it * 256 + t] = W4[it * 256 + t];
    }
    __syncthreads();

    const int wave = t >> 6, lane = t & 63;
    const int wg = blockIdx.x * 4 + wave;      // global wave id
    const int nw = gridDim.x * 4;

    // (a) self contributions from F1 list
    int f1 = cnt[2]; if (f1 > CAP_F1) f1 = CAP_F1;
    for (int idx = wg; idx < f1; idx += nw) {
        int v = F1[idx];
        float dv = degw(dm[v]);
        gemv_scatter(x, v, dv * dv, v, wsm, lane, AGG1);
    }

    // (b) edge scan: 4 edges per lane per round, ballot the rare hits
    const int nq = E >> 2;
    const int4* d4p = (const int4*)dst;
    const bool vec4 = ((((uintptr_t)dst) & 15) == 0);
    if (vec4) {
        for (int q0 = wg * 64; q0 < nq; q0 += nw * 64) {
            int q = q0 + lane;
            int4 d4 = make_int4(-1, -1, -1, -1);
            if (q < nq) d4 = d4p[q];
            #pragma unroll
            for (int sub = 0; sub < 4; ++sub) {
                int d = (sub == 0) ? d4.x : (sub == 1) ? d4.y : (sub == 2) ? d4.z : d4.w;
                bool hitb = false; int s = 0, dmd = 0;
                if (q < nq) {
                    dmd = dm[d];
                    hitb = (dmd & M1) != 0;
                    if (hitb) s = src[(q << 2) + sub];
                }
                unsigned long long m = __ballot(hitb);
                while (m) {
                    int j = __ffsll(m) - 1; m &= m - 1;
                    int sb = __shfl(s, j), db = __shfl(d, j), dv = __shfl(dmd, j);
                    float w = degw(dm[sb]) * degw(dv);
                    gemv_scatter(x, sb, w, db, wsm, lane, AGG1);
                }
            }
        }
        if (blockIdx.x == 0 && wave == 0) {
            for (int i = nq << 2; i < E; ++i) {
                int d = dst[i];
                int dmd = dm[d];
                if (dmd & M1) {
                    int s = src[i];
                    float w = degw(dm[s]) * degw(dmd);
                    gemv_scatter(x, s, w, d, wsm, lane, AGG1);
                }
            }
        }
    } else {
        for (int i0 = wg * 64; i0 < E; i0 += nw * 64) {
            int i = i0 + lane;
            bool hitb = false; int s = 0, d = -1, dmd = 0;
            if (i < E) {
                d = dst[i];
                dmd = dm[d];
                hitb = (dmd & M1) != 0;
                if (hitb) s = src[i];
            }
            unsigned long long m = __ballot(hitb);
            while (m) {
                int j = __ffsll(m) - 1; m &= m - 1;
                int sb = __shfl(s, j), db = __shfl(d, j), dv = __shfl(dmd, j);
                float w = degw(dm[sb]) * degw(dv);
                gemv_scatter(x, sb, w, db, wsm, lane, AGG1);
            }
        }
    }
}

// ---------------------------------------------------------------------------
// k_gemv2tail: multi-block layer-2 GEMV scatter (64 blocks), then the LAST
// block to finish runs the tail (layer-3 + FC) in-block.
// Done protocol: per-block vmcnt(0) + device-scope fetch_add; last arriver
// does one ACQUIRE load (L1 invalidate; pattern validated absmax=0 in r5-r8).
// ---------------------------------------------------------------------------
__global__ __launch_bounds__(256) void k_gemv2tail(
    const int2* __restrict__ E2l, const int2* __restrict__ E3l,
    int* __restrict__ cnt,
    const float* __restrict__ AGG1, const float* __restrict__ b1,
    const float* __restrict__ W2, const float* __restrict__ b2,
    const float* __restrict__ W3, const float* __restrict__ b3,
    const float* __restrict__ fcW, const float* __restrict__ fcb,
    const int* __restrict__ dm, int last,
    float* __restrict__ AGG2, float* __restrict__ out)
{
    __shared__ float wsm[128][128];
    __shared__ int isLast;
    const int t = threadIdx.x;
    const int wave = t >> 6, lane = t & 63;

    int e2 = cnt[3]; if (e2 > CAP_E2) e2 = CAP_E2;
    const bool active = ((int)blockIdx.x * 4 < e2);   // block-uniform
    if (active) {
        {   // stage W2
            const float4* W4 = (const float4*)W2;
            float4* S4 = (float4*)&wsm[0][0];
            #pragma unroll
            for (int it = 0; it < 16; ++it) S4[it * 256 + t] = W4[it * 256 + t];
        }
        __syncthreads();
        const int wstride = gridDim.x * 4;
        for (int e = blockIdx.x * 4 + wave; e < e2; e += wstride) {
            int2 ed = E2l[e];
            float w = degw(dm[ed.x]) * degw(dm[ed.y]);
            size_t so = (size_t)ed.x * NF;
            float x0 = fmaxf(AGG1[so + lane]      + b1[lane],      0.f);
            float x1 = fmaxf(AGG1[so + lane + 64] + b1[lane + 64], 0.f);
            float a0 = 0.f, a1 = 0.f;
            #pragma unroll 16
            for (int k = 0; k < 64; ++k) {
                float xk = __shfl(x0, k);
                a0 += xk * wsm[k][lane];
                a1 += xk * wsm[k][lane + 64];
            }
            #pragma unroll 16
            for (int k = 0; k < 64; ++k) {
                float xk = __shfl(x1, k);
                a0 += xk * wsm[k + 64][lane];
                a1 += xk * wsm[k + 64][lane + 64];
            }
            size_t off = (size_t)ed.y * NF;
            atomicAdd(&AGG2[off + lane],      w * a0);
            atomicAdd(&AGG2[off + lane + 64], w * a1);
        }
    }

    // ---- done protocol ----
    __syncthreads();
    if (t == 0) {
        asm volatile("s_waitcnt vmcnt(0)" ::: "memory");   // atomics committed
        int p = __hip_atomic_fetch_add(&cnt[8], 1, __ATOMIC_RELAXED,
                                       __HIP_MEMORY_SCOPE_AGENT);
        isLast = (p == (int)gridDim.x - 1);
        if (isLast)
            (void)__hip_atomic_load(&cnt[8], __ATOMIC_ACQUIRE,
                                    __HIP_MEMORY_SCOPE_AGENT);   // L1 invalidate
    }
    __syncthreads();
    if (!isLast) return;

    // ---- tail (this block only): layer-3 + FC ----
    {   // stage W3 (reuse LDS)
        const float4* W4 = (const float4*)W3;
        float4* S4 = (float4*)&wsm[0][0];
        #pragma unroll
        for (int it = 0; it < 16; ++it) S4[it * 256 + t] = W4[it * 256 + t];
    }
    __syncthreads();

    int e3 = cnt[1]; if (e3 > CAP_E3) e3 = CAP_E3;
    const float dl = degw(dm[last]);
    float acc0 = 0.f, acc1 = 0.f;
    for (int e = wave; e < e3; e += 4) {
        int s = E3l[e].x;
        float w = degw(dm[s]) * dl;
        size_t so = (size_t)s * NF;
        float x0 = fmaxf(AGG2[so + lane]      + b2[lane],      0.f);
        float x1 = fmaxf(AGG2[so + lane + 64] + b2[lane + 64], 0.f);
        float a0 = 0.f, a1 = 0.f;
        #pragma unroll 16
        for (int k = 0; k < 64; ++k) {
            float xk = __shfl(x0, k);
            a0 += xk * wsm[k][lane];
            a1 += xk * wsm[k][lane + 64];
        }
        #pragma unroll 16
        for (int k = 0; k < 64; ++k) {
            float xk = __shfl(x1, k);
            a0 += xk * wsm[k + 64][lane];
            a1 += xk * wsm[k + 64][lane + 64];
        }
        acc0 += w * a0;
        acc1 += w * a1;
    }
    __syncthreads();                     // all waves done reading W3
    wsm[wave][lane]      = acc0;         // reuse rows 0..3 as reduce buffer
    wsm[wave][lane + 64] = acc1;
    __syncthreads();
    if (t < NF) {
        float s4 = wsm[0][t] + wsm[1][t] + wsm[2][t] + wsm[3][t];
        wsm[8][t] = fmaxf(s4 + b3[t], 0.f);
    }
    __syncthreads();
    if (t < OUTF) {
        float acc = fcb[t];
        #pragma unroll 16
        for (int k = 0; k < NF; ++k) acc += wsm[8][k] * fcW[k * OUTF + t];
        out[t] = acc;
    }
}

// ---------------------------------------------------------------------------

extern "C" void kernel_launch(void* const* d_in, const int* in_sizes, int n_in,
                              void* d_out, int out_size, void* d_ws, size_t ws_size,
                              hipStream_t stream)
{
    const float* x    = (const float*)d_in[0];
    const int*   ei   = (const int*)d_in[1];
    const float* W1   = (const float*)d_in[2];
    const float* b1   = (const float*)d_in[3];
    const float* W2   = (const float*)d_in[4];
    const float* b2   = (const float*)d_in[5];
    const float* W3   = (const float*)d_in[6];
    const float* b3   = (const float*)d_in[7];
    const float* fcW  = (const float*)d_in[8];
    const float* fcb  = (const float*)d_in[9];
    float* out = (float*)d_out;

    const int n = in_sizes[0] / NF;       // 50000
    const int E = in_sizes[1] / 2;        // 600000
    const int* src = ei;
    const int* dst = ei + E;
    const int last = n - 1;

    char* wp = (char*)d_ws;
    auto alloc = [&](size_t bytes) -> void* {
        void* r = (void*)wp;
        wp += (bytes + 255) & ~(size_t)255;
        return r;
    };
    // zeroed region: dm | cnt  (one memset, ~200KB)
    int*   dm   = (int*)alloc((size_t)n * 4);
    int*   cnt  = (int*)alloc(64 * 4);
    size_t zbytes = (char*)wp - (char*)dm;

    int*   F2   = (int*) alloc(CAP_F2 * 4);
    int2*  E3   = (int2*)alloc(CAP_E3 * 8);
    int*   F1   = (int*) alloc(CAP_F1 * 4);
    int2*  E2   = (int2*)alloc(CAP_E2 * 8);
    float* AGG1 = (float*)alloc((size_t)n * NF * 4);
    float* AGG2 = (float*)alloc((size_t)n * NF * 4);

    hipMemsetAsync(dm, 0, zbytes, stream);

    const int B = 256;
    const int SB = ((E + 3) / 4 + B - 1) / B;

    k_scan1<<<SB, B, 0, stream>>>(src, dst, E, last, dm, cnt, F2, E3, E2, AGG2);
    k_scan2<<<SB, B, 0, stream>>>(src, dst, E, dm, cnt, F2, F1, E2, AGG1);
    k_l1   <<<256, B, 0, stream>>>(src, dst, E, dm, cnt, F1, x, W1, AGG1);
    k_gemv2tail<<<64, B, 0, stream>>>(E2, E3, cnt, AGG1, b1, W2, b2, W3, b3,
                                      fcW, fcb, dm, last, AGG2, out);
}